// Round 1
// baseline (360.683 us; speedup 1.0000x reference)
//
#include <hip/hip_runtime.h>
#include <hip/hip_bf16.h>
#include <stdint.h>

typedef __attribute__((ext_vector_type(4))) float  f32x4;
typedef __attribute__((ext_vector_type(8))) short  short8;
typedef __attribute__((ext_vector_type(8))) __bf16 bf16x8;

#define GLB_AS __attribute__((address_space(1)))
#define LDS_AS __attribute__((address_space(3)))

__device__ __forceinline__ float bf2f(ushort u) {
    union { uint u32; float f; } c; c.u32 = (uint)u << 16; return c.f;
}
__device__ __forceinline__ ushort f2bf(float f) {
    union { float f; uint u32; } c; c.f = f;
    uint x = c.u32;
    return (ushort)((x + 0x7fffu + ((x >> 16) & 1u)) >> 16);
}

__device__ __forceinline__ void storeC(float* p, float v)  { *p = v; }
__device__ __forceinline__ void storeC(ushort* p, float v) { *p = f2bf(v); }

// ---------------- fp32 -> bf16 convert ----------------
__global__ __launch_bounds__(256) void convert_f32_bf16(
    const float* __restrict__ in, ushort* __restrict__ out, long n)
{
    long i0 = ((long)blockIdx.x * 256 + threadIdx.x) * 8;
    long stride = (long)gridDim.x * 256 * 8;
    for (long i = i0; i < n; i += stride) {
        float4 a = *(const float4*)(in + i);
        float4 b = *(const float4*)(in + i + 4);
        short8 o;
        o[0] = (short)f2bf(a.x); o[1] = (short)f2bf(a.y);
        o[2] = (short)f2bf(a.z); o[3] = (short)f2bf(a.w);
        o[4] = (short)f2bf(b.x); o[5] = (short)f2bf(b.y);
        o[6] = (short)f2bf(b.z); o[7] = (short)f2bf(b.w);
        *(short8*)(out + i) = o;
    }
}

// ---------------- RoPE, in-place on bf16 q,k ----------------
// row = b*S + s, pos[row] = s.  Pair (2j,2j+1): out0 = t0*c - t1*s1; out1 = t1*c + t0*s1
__global__ __launch_bounds__(256) void rope_inplace(
    ushort* __restrict__ q, ushort* __restrict__ k, const float* __restrict__ pos)
{
    const int row = blockIdx.x;
    const float p = pos[row];
    const size_t base = (size_t)row * 1024;
    const int tid = threadIdx.x;
#pragma unroll
    for (int t = 0; t < 2; ++t) {
        int j = tid + t * 256;                       // pair index 0..511
        // omega = 10000^(-j/512) = 2^(-j*log2(10000)/512)
        float omega = exp2f(-(float)j * (13.287712379549449f / 512.0f));
        float ang = p * omega;
        float sn, cs;
        sincosf(ang, &sn, &cs);
        uint pq = *(uint*)(q + base + 2 * j);
        float q0 = bf2f((ushort)(pq & 0xffff)), q1 = bf2f((ushort)(pq >> 16));
        float r0 = q0 * cs - q1 * sn, r1 = q1 * cs + q0 * sn;
        *(uint*)(q + base + 2 * j) = (uint)f2bf(r0) | ((uint)f2bf(r1) << 16);
        uint pk = *(uint*)(k + base + 2 * j);
        float k0 = bf2f((ushort)(pk & 0xffff)), k1 = bf2f((ushort)(pk >> 16));
        float s0 = k0 * cs - k1 * sn, s1 = k1 * cs + k0 * sn;
        *(uint*)(k + base + 2 * j) = (uint)f2bf(s0) | ((uint)f2bf(s1) << 16);
    }
}

// ---------------- row softmax over 2048 bf16, in place ----------------
__global__ __launch_bounds__(256) void softmax_rows(ushort* __restrict__ P)
{
    const size_t base = (size_t)blockIdx.x * 2048;
    const int tid = threadIdx.x;
    const int lane = tid & 63, wid = tid >> 6;
    short8 v = *(const short8*)(P + base + tid * 8);
    float f[8];
#pragma unroll
    for (int j = 0; j < 8; ++j) f[j] = bf2f((ushort)v[j]);
    float mx = f[0];
#pragma unroll
    for (int j = 1; j < 8; ++j) mx = fmaxf(mx, f[j]);
#pragma unroll
    for (int o = 32; o; o >>= 1) mx = fmaxf(mx, __shfl_xor(mx, o, 64));
    __shared__ float redm[4], reds[4];
    if (lane == 0) redm[wid] = mx;
    __syncthreads();
    mx = fmaxf(fmaxf(redm[0], redm[1]), fmaxf(redm[2], redm[3]));
    float s = 0.f;
#pragma unroll
    for (int j = 0; j < 8; ++j) { f[j] = __expf(f[j] - mx); s += f[j]; }
#pragma unroll
    for (int o = 32; o; o >>= 1) s += __shfl_xor(s, o, 64);
    if (lane == 0) reds[wid] = s;
    __syncthreads();
    s = reds[0] + reds[1] + reds[2] + reds[3];
    float inv = 1.0f / s;
    short8 o8;
#pragma unroll
    for (int j = 0; j < 8; ++j) o8[j] = (short)f2bf(f[j] * inv);
    *(short8*)(P + base + tid * 8) = o8;
}

// ---------------- bf16 GEMM: C = A(MxK) @ B(NxK)^T [+bias] [scale/causal] ----------------
// 128x128 tile, BK=64, 4 waves (each 64x64 = 4x4 of 16x16x32 MFMA), global_load_lds staging.
template<bool BIAS_COL, bool BIAS_ROW, bool CAUSAL_MASK, bool CAUSAL_K, typename OutT>
__global__ __launch_bounds__(256, 2) void gemm_bt(
    const ushort* __restrict__ A, const ushort* __restrict__ B,
    OutT* __restrict__ C, const float* __restrict__ bias,
    int K, int lda, int ldb, int ldc,
    long sA, long sB, long sC, float scale)
{
    __shared__ ushort As[128 * 64];
    __shared__ ushort Bs[128 * 64];
    A += (long)blockIdx.z * sA;
    B += (long)blockIdx.z * sB;
    C += (long)blockIdx.z * sC;
    const int tid = threadIdx.x;
    const int lane = tid & 63;
    const int wid = tid >> 6;
    const int rowBase = blockIdx.y * 128;
    const int colBase = blockIdx.x * 128;
    const int wr = (wid >> 1) * 64;
    const int wc = (wid & 1) * 64;
    const int fr = lane & 15;      // frag row (A) / col (B)
    const int kg = lane >> 4;      // k-group

    f32x4 acc[4][4] = {};

    bool skip = false;
    if (CAUSAL_MASK) skip = (colBase > rowBase + 127);   // fully-masked tile
    int Kend = K;
    if (CAUSAL_K) { int ke = rowBase + 128; Kend = ke < K ? ke : K; }

    if (!skip) {
        const int sRow = lane >> 3;          // 0..7 within 8-row chunk
        const int sCol = (lane & 7) * 8;     // elem col within BK
        for (int k0 = 0; k0 < Kend; k0 += 64) {
            __syncthreads();
#pragma unroll
            for (int r = 0; r < 4; ++r) {
                const int chunk = wid * 4 + r;            // 16 x 1KB chunks per tile
                const ushort* ga = A + (size_t)(rowBase + chunk * 8 + sRow) * lda + k0 + sCol;
                __builtin_amdgcn_global_load_lds((const GLB_AS void*)ga,
                    (LDS_AS void*)(As + chunk * 512), 16, 0, 0);
                const ushort* gb = B + (size_t)(colBase + chunk * 8 + sRow) * ldb + k0 + sCol;
                __builtin_amdgcn_global_load_lds((const GLB_AS void*)gb,
                    (LDS_AS void*)(Bs + chunk * 512), 16, 0, 0);
            }
            __syncthreads();
#pragma unroll
            for (int kk = 0; kk < 64; kk += 32) {
                short8 a[4], b[4];
#pragma unroll
                for (int m = 0; m < 4; ++m)
                    a[m] = *(const short8*)&As[(wr + m * 16 + fr) * 64 + kk + kg * 8];
#pragma unroll
                for (int n = 0; n < 4; ++n)
                    b[n] = *(const short8*)&Bs[(wc + n * 16 + fr) * 64 + kk + kg * 8];
#pragma unroll
                for (int m = 0; m < 4; ++m)
#pragma unroll
                    for (int n = 0; n < 4; ++n)
                        acc[m][n] = __builtin_amdgcn_mfma_f32_16x16x32_bf16(
                            __builtin_bit_cast(bf16x8, a[m]),
                            __builtin_bit_cast(bf16x8, b[n]),
                            acc[m][n], 0, 0, 0);
            }
        }
    }

    // epilogue: C/D layout col = lane&15, row = (lane>>4)*4 + j
#pragma unroll
    for (int m = 0; m < 4; ++m) {
#pragma unroll
        for (int n = 0; n < 4; ++n) {
#pragma unroll
            for (int j = 0; j < 4; ++j) {
                int row = rowBase + wr + m * 16 + kg * 4 + j;
                int col = colBase + wc + n * 16 + fr;
                float v = acc[m][n][j] * scale;
                if (BIAS_COL) v += bias[col];
                if (BIAS_ROW) v += bias[row];
                if (CAUSAL_MASK && (col > row)) v = -1e7f;
                storeC(C + (size_t)row * ldc + col, v);
            }
        }
    }
}

// ---------------- host-side orchestration ----------------
extern "C" void kernel_launch(void* const* d_in, const int* in_sizes, int n_in,
                              void* d_out, int out_size, void* d_ws, size_t ws_size,
                              hipStream_t stream)
{
    const float* x   = (const float*)d_in[0];
    const float* pos = (const float*)d_in[1];
    // d_in[2] = mask (causal, known analytically) — unused
    const float* Wq = (const float*)d_in[3]; const float* bq = (const float*)d_in[4];
    const float* Wk = (const float*)d_in[5]; const float* bk = (const float*)d_in[6];
    const float* Wv = (const float*)d_in[7]; const float* bv = (const float*)d_in[8];
    const float* Wo = (const float*)d_in[9]; const float* bo = (const float*)d_in[10];
    float* out = (float*)d_out;

    const int S = 2048, E = 1024, H = 1024, Bz = 4;
    const int Mtot = Bz * S;   // 8192

    ushort* xb  = (ushort*)d_ws;            // 8192x1024
    ushort* wqb = xb  + (size_t)Mtot * E;   // 1024x1024
    ushort* wkb = wqb + (size_t)H * E;
    ushort* wvb = wkb + (size_t)H * E;
    ushort* wob = wvb + (size_t)H * E;
    ushort* qb  = wob + (size_t)H * H;      // 8192x1024 (reused as O later)
    ushort* kb  = qb  + (size_t)Mtot * H;
    ushort* vt  = kb  + (size_t)Mtot * H;   // 1024 x 8192  (VT[h][b*S+s])
    ushort* P   = vt  + (size_t)H * Mtot;   // 4 x 2048 x 2048
    ushort* O   = qb;                       // reuse (qb dead after QK^T)

    // bf16 conversions
    convert_f32_bf16<<<2048, 256, 0, stream>>>(x,  xb,  (long)Mtot * E);
    convert_f32_bf16<<<512,  256, 0, stream>>>(Wq, wqb, (long)H * E);
    convert_f32_bf16<<<512,  256, 0, stream>>>(Wk, wkb, (long)H * E);
    convert_f32_bf16<<<512,  256, 0, stream>>>(Wv, wvb, (long)H * E);
    convert_f32_bf16<<<512,  256, 0, stream>>>(Wo, wob, (long)H * H);

    // Q = x@Wq^T + bq ; K = x@Wk^T + bk   (bf16 out, rope'd in place next)
    dim3 gProj(H / 128, Mtot / 128, 1);
    gemm_bt<true, false, false, false, ushort><<<gProj, 256, 0, stream>>>(
        xb, wqb, qb, bq, E, E, E, H, 0, 0, 0, 1.0f);
    gemm_bt<true, false, false, false, ushort><<<gProj, 256, 0, stream>>>(
        xb, wkb, kb, bk, E, E, E, H, 0, 0, 0, 1.0f);
    // VT = Wv @ x^T + bv(row)  -> V transposed for free (B^T-form operand for PV)
    dim3 gVT(Mtot / 128, H / 128, 1);
    gemm_bt<false, true, false, false, ushort><<<gVT, 256, 0, stream>>>(
        wvb, xb, vt, bv, E, E, E, Mtot, 0, 0, 0, 1.0f);

    rope_inplace<<<Mtot, 256, 0, stream>>>(qb, kb, pos);

    // P = causal_mask(Q@K^T / 32)  (bf16), batched over 4
    dim3 gQK(S / 128, S / 128, Bz);
    gemm_bt<false, false, true, false, ushort><<<gQK, 256, 0, stream>>>(
        qb, kb, P, nullptr, H, H, H, S,
        (long)S * H, (long)S * H, (long)S * S, 0.03125f);

    softmax_rows<<<Mtot, 256, 0, stream>>>(P);

    // O = P @ VT^T  (bf16), K-loop clipped by causality
    dim3 gPV(H / 128, S / 128, Bz);
    gemm_bt<false, false, false, true, ushort><<<gPV, 256, 0, stream>>>(
        P, vt, O, nullptr, S, S, Mtot, H,
        (long)S * S, (long)S, (long)S * H, 1.0f);

    // out = O @ Wo^T + bo  (fp32 -> d_out)
    dim3 gOut(H / 128, Mtot / 128, 1);
    gemm_bt<true, false, false, false, float><<<gOut, 256, 0, stream>>>(
        O, wob, out, bo, H, H, H, H, 0, 0, 0, 1.0f);
}